// Round 4
// baseline (212.461 us; speedup 1.0000x reference)
//
#include <hip/hip_runtime.h>
#include <math.h>

#define DM 2048
#define NEXP 64
#define NTOK 16384
#define KC 32                  // k per chunk == one MFMA k-step
#define KSLW 256               // k per wave (one K-eighth)
#define NCHW (KSLW / KC)       // 8 chunks per wave
#define NWAVE 8                // waves per block
#define MBLK 32                // tokens per block (2 M-tiles of 16 per wave)
#define NBLK (NTOK / MBLK)     // 512 blocks
#define NKG (DM / KC)          // 64 global k-steps
#define WFRAG_BYTES (NKG * 12 * 1024)  // [kg][limb*4+nt][lane][16B] = 768 KB
#define QS 2120                // LDS partial stride in floats (32*66 + 8)

typedef __attribute__((ext_vector_type(8))) short short8;
typedef __attribute__((ext_vector_type(4))) short short4v;
typedef __attribute__((ext_vector_type(4))) float f32x4;

// Truncating 3-limb bf16 split: f = h+m+l, residual ~2^-24 rel.
__device__ __forceinline__ void split3t(float f, unsigned short& h,
                                        unsigned short& m, unsigned short& l) {
  unsigned u = __float_as_uint(f);
  h = (unsigned short)(u >> 16);
  float f1 = f - __uint_as_float(u & 0xFFFF0000u);
  unsigned u1 = __float_as_uint(f1);
  m = (unsigned short)(u1 >> 16);
  float f2 = f1 - __uint_as_float(u1 & 0xFFFF0000u);
  l = (unsigned short)(__float_as_uint(f2) >> 16);
}

__device__ __forceinline__ void split8(const f32x4& a0, const f32x4& a1,
                                       short8& h, short8& m, short8& l) {
  float v[8] = {a0[0], a0[1], a0[2], a0[3], a1[0], a1[1], a1[2], a1[3]};
#pragma unroll
  for (int j = 0; j < 8; ++j) {
    unsigned short hh, mm, ll;
    split3t(v[j], hh, mm, ll);
    h[j] = (short)hh; m[j] = (short)mm; l[j] = (short)ll;
  }
}

// Pre-split W into MFMA-B-fragment-ordered limb blocks (lane-indexed):
// wfrag[((kg*12 + limb*4 + nt)*64 + lane)*8 + j] =
//   limb of W[nt*16 + (lane&15)][kg*32 + (lane>>4)*8 + j]
__global__ void convw_kernel(const float* __restrict__ W,
                             unsigned short* __restrict__ wfrag) {
  const int kg = blockIdx.x;
  const int lane = threadIdx.x & 63;
  const int nt = threadIdx.x >> 6;
  const int e = nt * 16 + (lane & 15);
  const int kpos = kg * 32 + (lane >> 4) * 8;
  const f32x4* wp = (const f32x4*)(W + (size_t)e * DM + kpos);
  f32x4 w0 = wp[0], w1 = wp[1];
  short8 h, m, l;
  split8(w0, w1, h, m, l);
  size_t base = ((size_t)(kg * 12 + nt) * 64 + lane) * 8;
  *(short8*)(wfrag + base) = h;
  *(short8*)(wfrag + base + (size_t)4 * 64 * 8) = m;
  *(short8*)(wfrag + base + (size_t)8 * 64 * 8) = l;
}

// Fused router R10: 512-thread blocks, 8 waves x K-eighth, 16 waves/CU.
// Grid 512 x 512. Block = 32 tokens; wave wv owns K-eighth wv (256 k,
// 8 chunks) for all 32 tokens x 64 experts -> acc[2 mt][4 nt].
// vs R9 (4 waves x K-quarter, 8 waves/CU): same B-fragment L2 traffic
// (393 MB total, ~1.6 TB/s/XCD — under the ~4.3 TB/s per-XCD ceiling
// that sank R7's 786 MB variant), but 2x the waves/SIMD for latency
// hiding. A: global->reg MFMA-layout, 2-chunk named-reg double buffer.
// B: JIT loads (no manual dbuf — keeps VGPR <= 128 for the 4-waves/SIMD
// target; TLP + compiler hoisting cover the ~200cy L2 latency).
// Epilogue: 8 K-partials exchanged via LDS (67.8 KB/block; 2 blocks =
// 135.7 KB <= 160 KB/CU), pairwise (q, q+4) add, then the verified
// xor16/xor32 quarter-sum + serial top-2 on waves 0-1.
__global__ __launch_bounds__(512, 4)
void router_fused(const float* __restrict__ x,
                  const unsigned short* __restrict__ wfrag,
                  const float* __restrict__ bias, float* __restrict__ out) {
  const int lane = threadIdx.x & 63;
  const int wv = threadIdx.x >> 6;   // K-eighth 0..7
  const int col = lane & 15;
  const int quad = lane >> 4;
  const int tok0 = blockIdx.x * MBLK;
  const int kg0 = wv * NCHW;

  __shared__ float pl[NWAVE * QS];  // ~67.8 KB

  // A pointers for the wave's two M-tiles.
  const float* xp0 = x + (size_t)(tok0 + col) * DM + wv * KSLW + quad * 8;
  const float* xp1 = xp0 + (size_t)16 * DM;
  const unsigned short* bb = wfrag + (size_t)lane * 8;

  f32x4 acc[2][4];
#pragma unroll
  for (int mt = 0; mt < 2; ++mt)
#pragma unroll
    for (int nt = 0; nt < 4; ++nt) acc[mt][nt] = (f32x4){0.f, 0.f, 0.f, 0.f};

  // A prefetch pipeline: P = chunk c, Q = chunk c+1 (all names static).
  f32x4 P00 = ((const f32x4*)xp0)[0], P01 = ((const f32x4*)xp0)[1];
  f32x4 P10 = ((const f32x4*)xp1)[0], P11 = ((const f32x4*)xp1)[1];
  f32x4 Q00 = ((const f32x4*)(xp0 + KC))[0], Q01 = ((const f32x4*)(xp0 + KC))[1];
  f32x4 Q10 = ((const f32x4*)(xp1 + KC))[0], Q11 = ((const f32x4*)(xp1 + KC))[1];

#pragma unroll 2
  for (int c = 0; c < NCHW; ++c) {
    const int kg = kg0 + c;
    short8 ah0, am0, al0, ah1, am1, al1;
    split8(P00, P01, ah0, am0, al0);
    split8(P10, P11, ah1, am1, al1);
    P00 = Q00; P01 = Q01; P10 = Q10; P11 = Q11;
    if (c + 2 < NCHW) {  // uniform branch; guards x OOB on last 2 chunks
      const float* n0 = xp0 + (size_t)(c + 2) * KC;
      const float* n1 = xp1 + (size_t)(c + 2) * KC;
      Q00 = ((const f32x4*)n0)[0]; Q01 = ((const f32x4*)n0)[1];
      Q10 = ((const f32x4*)n1)[0]; Q11 = ((const f32x4*)n1)[1];
    }
#pragma unroll
    for (int nt = 0; nt < 4; ++nt) {
      // JIT B limb loads for nt-group (g, g+4, g+8); all indices in-range
      // (max g+8 = 63*12+3+8 = 767 < 768) -> no wfrag overrun.
      const int g = kg * 12 + nt;
      short8 bh = *(const short8*)(bb + (size_t)(g + 0) * 512);
      short8 bm = *(const short8*)(bb + (size_t)(g + 4) * 512);
      short8 bl = *(const short8*)(bb + (size_t)(g + 8) * 512);
      {
        f32x4 cc = acc[0][nt];
        cc = __builtin_amdgcn_mfma_f32_16x16x32_bf16(ah0, bh, cc, 0, 0, 0);
        cc = __builtin_amdgcn_mfma_f32_16x16x32_bf16(ah0, bm, cc, 0, 0, 0);
        cc = __builtin_amdgcn_mfma_f32_16x16x32_bf16(am0, bh, cc, 0, 0, 0);
        cc = __builtin_amdgcn_mfma_f32_16x16x32_bf16(ah0, bl, cc, 0, 0, 0);
        cc = __builtin_amdgcn_mfma_f32_16x16x32_bf16(al0, bh, cc, 0, 0, 0);
        cc = __builtin_amdgcn_mfma_f32_16x16x32_bf16(am0, bm, cc, 0, 0, 0);
        acc[0][nt] = cc;
      }
      {
        f32x4 cc = acc[1][nt];
        cc = __builtin_amdgcn_mfma_f32_16x16x32_bf16(ah1, bh, cc, 0, 0, 0);
        cc = __builtin_amdgcn_mfma_f32_16x16x32_bf16(ah1, bm, cc, 0, 0, 0);
        cc = __builtin_amdgcn_mfma_f32_16x16x32_bf16(am1, bh, cc, 0, 0, 0);
        cc = __builtin_amdgcn_mfma_f32_16x16x32_bf16(ah1, bl, cc, 0, 0, 0);
        cc = __builtin_amdgcn_mfma_f32_16x16x32_bf16(al1, bh, cc, 0, 0, 0);
        cc = __builtin_amdgcn_mfma_f32_16x16x32_bf16(am1, bm, cc, 0, 0, 0);
        acc[1][nt] = cc;
      }
    }
  }

  // ---- exchange K-eighth partials via LDS ----
  // pl[wv*QS + t_local*66 + e]; QS%32==8 and 66%32==2 keep the write
  // pattern (col+8*quad) at 2-way; epilogue read ~4-way (sub-us, ok).
#pragma unroll
  for (int mt = 0; mt < 2; ++mt)
#pragma unroll
    for (int nt = 0; nt < 4; ++nt)
#pragma unroll
      for (int r = 0; r < 4; ++r)
        pl[wv * QS + (mt * 16 + quad * 4 + r) * 66 + nt * 16 + col] =
            acc[mt][nt][r];
  __syncthreads();

  // ---- top-2: waves 0-1, lane=(q, token16); p = eighth q + eighth q+4,
  // then the verified xor16/xor32 quarter-sum + serial top-2 chain ----
  if (wv < 2) {
    const int tt = lane & 15;
    const int q = lane >> 4;
    const int tl = wv * 16 + tt;  // local token 0..31
    float v1 = -INFINITY, v2 = -INFINITY;
    int i1 = 0, i2 = 0;
#pragma unroll
    for (int e = 0; e < NEXP; ++e) {
      float p = pl[q * QS + tl * 66 + e] + pl[(q + 4) * QS + tl * 66 + e];
      p += __shfl_xor(p, 16, 64);
      p += __shfl_xor(p, 32, 64);
      const float v = p + bias[e];
      const bool a = v > v1;
      const bool b = v > v2;
      const float nv2 = a ? v1 : (b ? v : v2);
      const int ni2 = a ? i1 : (b ? e : i2);
      v2 = nv2; i2 = ni2;
      i1 = a ? e : i1;
      v1 = a ? v : v1;
    }
    if (q == 0) {
      const int t = tok0 + tl;
      const float ex = expf(v2 - v1);
      const float den = 1.f + ex;
      *(float2*)(out + 2 * t) = make_float2(1.f / den, ex / den);
      *(float2*)(out + 2 * NTOK + 2 * t) = make_float2((float)i1, (float)i2);
    }
  }
}

// Fallback (ws too small): verified single-kernel path, inline W split.
__global__ __launch_bounds__(512, 2)
void router_fb(const float* __restrict__ x, const float* __restrict__ W,
               const float* __restrict__ bias, float* __restrict__ out) {
  const int lane = threadIdx.x & 63;
  const int wv = threadIdx.x >> 6;
  const int col = lane & 15;
  const int quad = lane >> 4;
  const int tok0 = blockIdx.x * 32;
  const int k0 = wv * 256;

  __shared__ float part[8][32][68];

  f32x4 acc[2][4];
#pragma unroll
  for (int ms = 0; ms < 2; ++ms)
#pragma unroll
    for (int nt = 0; nt < 4; ++nt) acc[ms][nt] = (f32x4){0.f, 0.f, 0.f, 0.f};

  for (int ks = 0; ks < 8; ++ks) {
    const int k = k0 + ks * 32 + quad * 8;
    short8 ah[2], am2[2], al2[2];
#pragma unroll
    for (int ms = 0; ms < 2; ++ms) {
      const f32x4* ap = (const f32x4*)(x + (size_t)(tok0 + ms * 16 + col) * DM + k);
      f32x4 a0 = ap[0], a1 = ap[1];
      split8(a0, a1, ah[ms], am2[ms], al2[ms]);
    }
#pragma unroll
    for (int nt = 0; nt < 4; ++nt) {
      short8 bh, bm, bl;
      const f32x4* wp = (const f32x4*)(W + (size_t)(nt * 16 + col) * DM + k);
      f32x4 w0 = wp[0], w1 = wp[1];
      split8(w0, w1, bh, bm, bl);
#pragma unroll
      for (int ms = 0; ms < 2; ++ms) {
        f32x4 cc = acc[ms][nt];
        cc = __builtin_amdgcn_mfma_f32_16x16x32_bf16(ah[ms], bh, cc, 0, 0, 0);
        cc = __builtin_amdgcn_mfma_f32_16x16x32_bf16(ah[ms], bm, cc, 0, 0, 0);
        cc = __builtin_amdgcn_mfma_f32_16x16x32_bf16(am2[ms], bh, cc, 0, 0, 0);
        cc = __builtin_amdgcn_mfma_f32_16x16x32_bf16(ah[ms], bl, cc, 0, 0, 0);
        cc = __builtin_amdgcn_mfma_f32_16x16x32_bf16(al2[ms], bh, cc, 0, 0, 0);
        cc = __builtin_amdgcn_mfma_f32_16x16x32_bf16(am2[ms], bm, cc, 0, 0, 0);
        acc[ms][nt] = cc;
      }
    }
  }
#pragma unroll
  for (int ms = 0; ms < 2; ++ms)
#pragma unroll
    for (int nt = 0; nt < 4; ++nt)
#pragma unroll
      for (int r = 0; r < 4; ++r)
        part[wv][ms * 16 + quad * 4 + r][nt * 16 + col] = acc[ms][nt][r];
  __syncthreads();
  const float bl_ = bias[lane];
#pragma unroll
  for (int ti = 0; ti < 4; ++ti) {
    const int t = wv * 4 + ti;
    float v1 = bl_;
#pragma unroll
    for (int p = 0; p < 8; ++p) v1 += part[p][t][lane];
    int i1 = lane;
    float v2 = -INFINITY;
    int i2 = NEXP;
#pragma unroll
    for (int off = 32; off > 0; off >>= 1) {
      float ov1 = __shfl_xor(v1, off, 64);
      int   oi1 = __shfl_xor(i1, off, 64);
      float ov2 = __shfl_xor(v2, off, 64);
      int   oi2 = __shfl_xor(i2, off, 64);
      bool afirst = (v1 > ov1) || (v1 == ov1 && i1 < oi1);
      float w1v = afirst ? v1 : ov1;  int w1i = afirst ? i1 : oi1;
      float c1v = afirst ? v2 : ov2;  int c1i = afirst ? i2 : oi2;
      float c2v = afirst ? ov1 : v1;  int c2i = afirst ? oi1 : i1;
      bool sfirst = (c1v > c2v) || (c1v == c2v && c1i < c2i);
      v1 = w1v; i1 = w1i;
      v2 = sfirst ? c1v : c2v;
      i2 = sfirst ? c1i : c2i;
    }
    if (lane == 0) {
      const float ex = expf(v2 - v1);
      const float den = 1.f + ex;
      const int token = tok0 + t;
      *(float2*)(out + 2 * token) = make_float2(1.f / den, ex / den);
      *(float2*)(out + 2 * NTOK + 2 * token) =
          make_float2((float)i1, (float)i2);
    }
  }
}

extern "C" void kernel_launch(void* const* d_in, const int* in_sizes, int n_in,
                              void* d_out, int out_size, void* d_ws, size_t ws_size,
                              hipStream_t stream) {
  const float* x = (const float*)d_in[0];
  const float* W = (const float*)d_in[1];
  const float* b = (const float*)d_in[2];
  float* out = (float*)d_out;

  const size_t need = (size_t)WFRAG_BYTES + 16384;
  if (ws_size >= need) {
    unsigned short* wfrag = (unsigned short*)d_ws;
    hipLaunchKernelGGL(convw_kernel, dim3(NKG), dim3(256), 0, stream, W, wfrag);
    hipLaunchKernelGGL(router_fused, dim3(NBLK), dim3(512), 0, stream,
                       x, wfrag, b, out);
  } else {
    hipLaunchKernelGGL(router_fb, dim3(NTOK / 32), dim3(512), 0, stream,
                       x, W, b, out);
  }
}

// Round 5
// 210.824 us; speedup vs baseline: 1.0078x; 1.0078x over previous
//
#include <hip/hip_runtime.h>
#include <math.h>

#define DM 2048
#define NEXP 64
#define NTOK 16384
#define KC 32                  // k per chunk == one MFMA k-step
#define KSL 512                // k per wave (one K-quarter)
#define NCH (KSL / KC)         // 16 chunks per wave
#define MBLK 32                // tokens per block (2 M-tiles of 16 per wave)
#define NBLK (NTOK / MBLK)     // 512 blocks
#define NKG (DM / KC)          // 64 global k-steps
#define WFRAG_BYTES (NKG * 12 * 1024)  // [kg][limb*4+nt][lane][16B] = 768 KB
#define QS 2120                // LDS partial q-stride in floats (32*66 + 8)

typedef __attribute__((ext_vector_type(8))) short short8;
typedef __attribute__((ext_vector_type(4))) short short4v;
typedef __attribute__((ext_vector_type(4))) float f32x4;

// Truncating 3-limb bf16 split: f = h+m+l, residual ~2^-24 rel.
__device__ __forceinline__ void split3t(float f, unsigned short& h,
                                        unsigned short& m, unsigned short& l) {
  unsigned u = __float_as_uint(f);
  h = (unsigned short)(u >> 16);
  float f1 = f - __uint_as_float(u & 0xFFFF0000u);
  unsigned u1 = __float_as_uint(f1);
  m = (unsigned short)(u1 >> 16);
  float f2 = f1 - __uint_as_float(u1 & 0xFFFF0000u);
  l = (unsigned short)(__float_as_uint(f2) >> 16);
}

__device__ __forceinline__ void split8(const f32x4& a0, const f32x4& a1,
                                       short8& h, short8& m, short8& l) {
  float v[8] = {a0[0], a0[1], a0[2], a0[3], a1[0], a1[1], a1[2], a1[3]};
#pragma unroll
  for (int j = 0; j < 8; ++j) {
    unsigned short hh, mm, ll;
    split3t(v[j], hh, mm, ll);
    h[j] = (short)hh; m[j] = (short)mm; l[j] = (short)ll;
  }
}

// Pre-split W into MFMA-B-fragment-ordered limb blocks (lane-indexed):
// wfrag[((kg*12 + limb*4 + nt)*64 + lane)*8 + j] =
//   limb of W[nt*16 + (lane&15)][kg*32 + (lane>>4)*8 + j]
__global__ void convw_kernel(const float* __restrict__ W,
                             unsigned short* __restrict__ wfrag) {
  const int kg = blockIdx.x;
  const int lane = threadIdx.x & 63;
  const int nt = threadIdx.x >> 6;
  const int e = nt * 16 + (lane & 15);
  const int kpos = kg * 32 + (lane >> 4) * 8;
  const f32x4* wp = (const f32x4*)(W + (size_t)e * DM + kpos);
  f32x4 w0 = wp[0], w1 = wp[1];
  short8 h, m, l;
  split8(w0, w1, h, m, l);
  size_t base = ((size_t)(kg * 12 + nt) * 64 + lane) * 8;
  *(short8*)(wfrag + base) = h;
  *(short8*)(wfrag + base + (size_t)4 * 64 * 8) = m;
  *(short8*)(wfrag + base + (size_t)8 * 64 * 8) = l;
}

// Fused router R11 = R9 structure + occupancy fix.
// 256-thread blocks, 4 waves x K-quarter, __launch_bounds__(256,4) ->
// 4 blocks/CU (LDS 4x34KB=136KB <= 160KB) = 16 waves/CU, VGPR cap 128.
// To fit 128 cleanly (R10 showed starvation at tight caps is catastrophic:
// VGPR collapsed to 64, scratch round-trips, 170us with all pipes <5%),
// B limbs are JIT-loaded (R10's verified in-range g,g+4,g+8 indexing;
// persistent regs = acc 32 + A-dbuf 32 = 64, peak ~112). The doubled TLP
// (16 vs 8 waves/CU) covers the ~200cy L2 latency the old B-prefetch hid;
// the 2-chunk A-dbuf still covers the ~900cy x latency.
// Numerics identical to verified R9: same values, same accumulation order.
__global__ __launch_bounds__(256, 4)
void router_fused(const float* __restrict__ x,
                  const unsigned short* __restrict__ wfrag,
                  const float* __restrict__ bias, float* __restrict__ out) {
  const int lane = threadIdx.x & 63;
  const int wv = threadIdx.x >> 6;   // K-quarter
  const int col = lane & 15;
  const int quad = lane >> 4;
  const int tok0 = blockIdx.x * MBLK;
  const int kg0 = wv * NCH;

  __shared__ float pl[4 * QS];  // ~33.9 KB

  // A pointers for the wave's two M-tiles.
  const float* xp0 = x + (size_t)(tok0 + col) * DM + wv * KSL + quad * 8;
  const float* xp1 = xp0 + (size_t)16 * DM;
  const unsigned short* bb = wfrag + (size_t)lane * 8;

  f32x4 acc[2][4];
#pragma unroll
  for (int mt = 0; mt < 2; ++mt)
#pragma unroll
    for (int nt = 0; nt < 4; ++nt) acc[mt][nt] = (f32x4){0.f, 0.f, 0.f, 0.f};

  // A prefetch pipeline: P = chunk c, Q = chunk c+1 (all names static).
  f32x4 P00 = ((const f32x4*)xp0)[0], P01 = ((const f32x4*)xp0)[1];
  f32x4 P10 = ((const f32x4*)xp1)[0], P11 = ((const f32x4*)xp1)[1];
  f32x4 Q00 = ((const f32x4*)(xp0 + KC))[0], Q01 = ((const f32x4*)(xp0 + KC))[1];
  f32x4 Q10 = ((const f32x4*)(xp1 + KC))[0], Q11 = ((const f32x4*)(xp1 + KC))[1];

#pragma unroll 2
  for (int c = 0; c < NCH; ++c) {
    const int kg = kg0 + c;
    short8 ah0, am0, al0, ah1, am1, al1;
    split8(P00, P01, ah0, am0, al0);
    split8(P10, P11, ah1, am1, al1);
    P00 = Q00; P01 = Q01; P10 = Q10; P11 = Q11;
    if (c + 2 < NCH) {  // uniform branch; guards x OOB on last 2 chunks
      const float* n0 = xp0 + (size_t)(c + 2) * KC;
      const float* n1 = xp1 + (size_t)(c + 2) * KC;
      Q00 = ((const f32x4*)n0)[0]; Q01 = ((const f32x4*)n0)[1];
      Q10 = ((const f32x4*)n1)[0]; Q11 = ((const f32x4*)n1)[1];
    }
#pragma unroll
    for (int nt = 0; nt < 4; ++nt) {
      // JIT B limb loads for nt-group (g, g+4, g+8); all indices in-range
      // (max g+8 = 63*12+3+8 = 767 < 768) -> no wfrag overrun.
      const int g = kg * 12 + nt;
      short8 bh = *(const short8*)(bb + (size_t)(g + 0) * 512);
      short8 bm = *(const short8*)(bb + (size_t)(g + 4) * 512);
      short8 bl = *(const short8*)(bb + (size_t)(g + 8) * 512);
      {
        f32x4 cc = acc[0][nt];
        cc = __builtin_amdgcn_mfma_f32_16x16x32_bf16(ah0, bh, cc, 0, 0, 0);
        cc = __builtin_amdgcn_mfma_f32_16x16x32_bf16(ah0, bm, cc, 0, 0, 0);
        cc = __builtin_amdgcn_mfma_f32_16x16x32_bf16(am0, bh, cc, 0, 0, 0);
        cc = __builtin_amdgcn_mfma_f32_16x16x32_bf16(ah0, bl, cc, 0, 0, 0);
        cc = __builtin_amdgcn_mfma_f32_16x16x32_bf16(al0, bh, cc, 0, 0, 0);
        cc = __builtin_amdgcn_mfma_f32_16x16x32_bf16(am0, bm, cc, 0, 0, 0);
        acc[0][nt] = cc;
      }
      {
        f32x4 cc = acc[1][nt];
        cc = __builtin_amdgcn_mfma_f32_16x16x32_bf16(ah1, bh, cc, 0, 0, 0);
        cc = __builtin_amdgcn_mfma_f32_16x16x32_bf16(ah1, bm, cc, 0, 0, 0);
        cc = __builtin_amdgcn_mfma_f32_16x16x32_bf16(am1, bh, cc, 0, 0, 0);
        cc = __builtin_amdgcn_mfma_f32_16x16x32_bf16(ah1, bl, cc, 0, 0, 0);
        cc = __builtin_amdgcn_mfma_f32_16x16x32_bf16(al1, bh, cc, 0, 0, 0);
        cc = __builtin_amdgcn_mfma_f32_16x16x32_bf16(am1, bm, cc, 0, 0, 0);
        acc[1][nt] = cc;
      }
    }
  }

  // ---- exchange K-quarter partials via LDS ----
  // pl[wv*QS + t_local*66 + e]; QS%32==8 and 66%32==2 keep both the
  // write pattern (col+8*quad) and read pattern (8q+2tt) at 2-way.
#pragma unroll
  for (int mt = 0; mt < 2; ++mt)
#pragma unroll
    for (int nt = 0; nt < 4; ++nt)
#pragma unroll
      for (int r = 0; r < 4; ++r)
        pl[wv * QS + (mt * 16 + quad * 4 + r) * 66 + nt * 16 + col] =
            acc[mt][nt][r];
  __syncthreads();

  // ---- top-2 (verified serial chain): waves 0-1, lane=(q, token16) ----
  if (wv < 2) {
    const int tt = lane & 15;
    const int q = lane >> 4;
    const int tl = wv * 16 + tt;  // local token 0..31
    float v1 = -INFINITY, v2 = -INFINITY;
    int i1 = 0, i2 = 0;
#pragma unroll
    for (int e = 0; e < NEXP; ++e) {
      float p = pl[q * QS + tl * 66 + e];
      p += __shfl_xor(p, 16, 64);
      p += __shfl_xor(p, 32, 64);
      const float v = p + bias[e];
      const bool a = v > v1;
      const bool b = v > v2;
      const float nv2 = a ? v1 : (b ? v : v2);
      const int ni2 = a ? i1 : (b ? e : i2);
      v2 = nv2; i2 = ni2;
      i1 = a ? e : i1;
      v1 = a ? v : v1;
    }
    if (q == 0) {
      const int t = tok0 + tl;
      const float ex = expf(v2 - v1);
      const float den = 1.f + ex;
      *(float2*)(out + 2 * t) = make_float2(1.f / den, ex / den);
      *(float2*)(out + 2 * NTOK + 2 * t) = make_float2((float)i1, (float)i2);
    }
  }
}

// Fallback (ws too small): verified single-kernel path, inline W split.
__global__ __launch_bounds__(512, 2)
void router_fb(const float* __restrict__ x, const float* __restrict__ W,
               const float* __restrict__ bias, float* __restrict__ out) {
  const int lane = threadIdx.x & 63;
  const int wv = threadIdx.x >> 6;
  const int col = lane & 15;
  const int quad = lane >> 4;
  const int tok0 = blockIdx.x * 32;
  const int k0 = wv * 256;

  __shared__ float part[8][32][68];

  f32x4 acc[2][4];
#pragma unroll
  for (int ms = 0; ms < 2; ++ms)
#pragma unroll
    for (int nt = 0; nt < 4; ++nt) acc[ms][nt] = (f32x4){0.f, 0.f, 0.f, 0.f};

  for (int ks = 0; ks < 8; ++ks) {
    const int k = k0 + ks * 32 + quad * 8;
    short8 ah[2], am2[2], al2[2];
#pragma unroll
    for (int ms = 0; ms < 2; ++ms) {
      const f32x4* ap = (const f32x4*)(x + (size_t)(tok0 + ms * 16 + col) * DM + k);
      f32x4 a0 = ap[0], a1 = ap[1];
      split8(a0, a1, ah[ms], am2[ms], al2[ms]);
    }
#pragma unroll
    for (int nt = 0; nt < 4; ++nt) {
      short8 bh, bm, bl;
      const f32x4* wp = (const f32x4*)(W + (size_t)(nt * 16 + col) * DM + k);
      f32x4 w0 = wp[0], w1 = wp[1];
      split8(w0, w1, bh, bm, bl);
#pragma unroll
      for (int ms = 0; ms < 2; ++ms) {
        f32x4 cc = acc[ms][nt];
        cc = __builtin_amdgcn_mfma_f32_16x16x32_bf16(ah[ms], bh, cc, 0, 0, 0);
        cc = __builtin_amdgcn_mfma_f32_16x16x32_bf16(ah[ms], bm, cc, 0, 0, 0);
        cc = __builtin_amdgcn_mfma_f32_16x16x32_bf16(am2[ms], bh, cc, 0, 0, 0);
        cc = __builtin_amdgcn_mfma_f32_16x16x32_bf16(ah[ms], bl, cc, 0, 0, 0);
        cc = __builtin_amdgcn_mfma_f32_16x16x32_bf16(al2[ms], bh, cc, 0, 0, 0);
        cc = __builtin_amdgcn_mfma_f32_16x16x32_bf16(am2[ms], bm, cc, 0, 0, 0);
        acc[ms][nt] = cc;
      }
    }
  }
#pragma unroll
  for (int ms = 0; ms < 2; ++ms)
#pragma unroll
    for (int nt = 0; nt < 4; ++nt)
#pragma unroll
      for (int r = 0; r < 4; ++r)
        part[wv][ms * 16 + quad * 4 + r][nt * 16 + col] = acc[ms][nt][r];
  __syncthreads();
  const float bl_ = bias[lane];
#pragma unroll
  for (int ti = 0; ti < 4; ++ti) {
    const int t = wv * 4 + ti;
    float v1 = bl_;
#pragma unroll
    for (int p = 0; p < 8; ++p) v1 += part[p][t][lane];
    int i1 = lane;
    float v2 = -INFINITY;
    int i2 = NEXP;
#pragma unroll
    for (int off = 32; off > 0; off >>= 1) {
      float ov1 = __shfl_xor(v1, off, 64);
      int   oi1 = __shfl_xor(i1, off, 64);
      float ov2 = __shfl_xor(v2, off, 64);
      int   oi2 = __shfl_xor(i2, off, 64);
      bool afirst = (v1 > ov1) || (v1 == ov1 && i1 < oi1);
      float w1v = afirst ? v1 : ov1;  int w1i = afirst ? i1 : oi1;
      float c1v = afirst ? v2 : ov2;  int c1i = afirst ? i2 : oi2;
      float c2v = afirst ? ov1 : v1;  int c2i = afirst ? oi1 : i1;
      bool sfirst = (c1v > c2v) || (c1v == c2v && c1i < c2i);
      v1 = w1v; i1 = w1i;
      v2 = sfirst ? c1v : c2v;
      i2 = sfirst ? c1i : c2i;
    }
    if (lane == 0) {
      const float ex = expf(v2 - v1);
      const float den = 1.f + ex;
      const int token = tok0 + t;
      *(float2*)(out + 2 * token) = make_float2(1.f / den, ex / den);
      *(float2*)(out + 2 * NTOK + 2 * token) =
          make_float2((float)i1, (float)i2);
    }
  }
}

extern "C" void kernel_launch(void* const* d_in, const int* in_sizes, int n_in,
                              void* d_out, int out_size, void* d_ws, size_t ws_size,
                              hipStream_t stream) {
  const float* x = (const float*)d_in[0];
  const float* W = (const float*)d_in[1];
  const float* b = (const float*)d_in[2];
  float* out = (float*)d_out;

  const size_t need = (size_t)WFRAG_BYTES + 16384;
  if (ws_size >= need) {
    unsigned short* wfrag = (unsigned short*)d_ws;
    hipLaunchKernelGGL(convw_kernel, dim3(NKG), dim3(256), 0, stream, W, wfrag);
    hipLaunchKernelGGL(router_fused, dim3(NBLK), dim3(256), 0, stream,
                       x, wfrag, b, out);
  } else {
    hipLaunchKernelGGL(router_fb, dim3(NTOK / 32), dim3(512), 0, stream,
                       x, W, b, out);
  }
}